// Round 9
// baseline (152.128 us; speedup 1.0000x reference)
//
#include <hip/hip_runtime.h>
#include <stdint.h>

// VP_lattice reverse step, B = 2^20 rows. Round-12:
//  R11 post-mortem: NT policy helped (<40us, fell out of top-5) but the
//  ~2TB/s read wall stands. Common trait of all prior variants: 16384
//  short-lived waves, each eating ONE full congested read latency that
//  overlaps only other waves' compute (38% occ). The 6.5TB/s fills are
//  persistent-style: few waves, continuous memory stream.
//  R12: persistent waves + double-buffered DMA pipeline.
//   - grid=512 (exactly 2 resident blocks/CU @ 57KB LDS), 2048 waves,
//     8 chunks/wave, STRIDED chunk assignment (waves march together).
//   - Per chunk: verified 7x dma16nt stream. DMA(k+1) issued BEFORE
//     compute(k) -> 7KB always in flight per wave; read latency hidden
//     under previous chunk's compute. 56KB in flight/CU >> 22KB needed
//     for 6.3TB/s.
//   - cf gather ordered BEFORE DMA issue (sched_barrier fences) so its
//     auto-waitcnt resolves at vmcnt(7), never draining the prefetch.
//   - vmcnt(0)+sched_barrier at top of each iteration = the only drain;
//     at that point only DMA(k)+3 old NT stores are outstanding.
//  Math + DMA stream byte-identical to R10/R11 (passed, absmax 0.0156).

#define NUM_STEPS 1000
#define TBL 1008
#define BLOCK 256
#define WAVES 4
#define GRID 512             // 2 blocks/CU on 256 CUs

// per-wave LDS stream layout (floats); byte size 7168
#define W_PLAT 0             // 576 f  (2304 B)   stream [0,2304)
#define W_LT   576           // 384 f  (1536 B)   stream [2304,3840)
#define W_PL0  960           // 384 f             stream [3840,5376)
#define W_ZN   1344          // 384 f             stream [5376,6912)
#define W_T    1728          // 64 i              stream [6912,7168)
#define W_SZF  1792          // floats per buffer
#define AS1 __attribute__((address_space(1)))
#define AS3 __attribute__((address_space(3)))

typedef float v2f __attribute__((ext_vector_type(2)));

// NT (non-temporal) DMA: aux=2 sets the NT CPol bit -> L1 no-allocate.
__device__ __forceinline__ void dma16nt(const void* g, void* s) {
    __builtin_amdgcn_global_load_lds((const AS1 void*)g, (AS3 void*)s, 16, 0, 2);
}

// ---------------- schedule pre-kernel (runs once) ----------------
__global__ __launch_bounds__(256) void sched_kernel(
    const float* __restrict__ alpha_bars,
    const float* __restrict__ betas,
    const float* __restrict__ sigmas,
    float4* __restrict__ ws)         // packed {A, B, S, 0} per timestep
{
    int j = blockIdx.x * blockDim.x + threadIdx.x;
    if (j >= TBL) return;
    float4 v = make_float4(0.f, 0.f, 0.f, 0.f);
    if (j <= NUM_STEPS) {
        float beta_last = betas[NUM_STEPS - 1];              // betas[-2]
        float alpha = 1.0f - fminf(betas[j], beta_last);     // clamp_min
        float coef  = 1.0f / sqrtf(alpha + 1e-8f);
        float scale = (1.0f - alpha) / sqrtf(1.0f - alpha_bars[j] + 1e-8f);
        v.x = coef * (1.0f - scale);                         // A
        v.y = 0.5f * coef * scale;                           // B
        v.z = (j > 1) ? sigmas[j] : 0.0f;                    // S (z-gated)
    }
    ws[j] = v;
}

// ---- stage one 64-row chunk into a wave buffer (7x dma16nt) ----
__device__ __forceinline__ void stage_chunk(
    const float* __restrict__ lt,  const float* __restrict__ pl0,
    const float* __restrict__ plat, const float* __restrict__ z_noise,
    const int* __restrict__ t, int rowW, int lane, float* w)
{
    const char* pP = (const char*)(plat    + (size_t)rowW * 9);  // 2304 B
    const char* pL = (const char*)(lt      + (size_t)rowW * 6);  // 1536 B
    const char* pQ = (const char*)(pl0     + (size_t)rowW * 6);
    const char* pZ = (const char*)(z_noise + (size_t)rowW * 6);
    const char* pT = (const char*)(t + rowW);                    // 256 B
    char* wb = (char*)w;
    const int lb = lane * 16;
    // stream s = k*1024 + lane*16; boundaries P|L|Q|Z|T at
    // 2304|3840|5376|6912|7168 — per-lane source select (16B-aligned).
    dma16nt(pP + lb,        wb       );                      // k0: P
    dma16nt(pP + 1024 + lb, wb + 1024);                      // k1: P
    { int s = 2048 + lb;                                     // k2: P|L
      dma16nt((s < 2304) ? pP + s : pL + (s - 2304), wb + 2048); }
    { int s = 3072 + lb;                                     // k3: L|Q
      dma16nt((s < 3840) ? pL + (s - 2304) : pQ + (s - 3840), wb + 3072); }
    dma16nt(pQ + 256 + lb,  wb + 4096);                      // k4: Q
    { int s = 5120 + lb;                                     // k5: Q|Z
      dma16nt((s < 5376) ? pQ + (s - 3840) : pZ + (s - 5376), wb + 5120); }
    { int s = 6144 + lb;                                     // k6: Z|T
      dma16nt((s < 6912) ? pZ + (s - 5376) : pT + (s - 6912), wb + 6144); }
}

// ---- per-row math: vec = upper-tri of sqrtm(A^T A) ----
__device__ __forceinline__ void sqrtm_vec(const float* pr, float vv[6])
{
    float a00 = pr[0], a01 = pr[1], a02 = pr[2];
    float a10 = pr[3], a11 = pr[4], a12 = pr[5];
    float a20 = pr[6], a21 = pr[7], a22 = pr[8];

    float m00 = a00*a00 + a10*a10 + a20*a20;
    float m01 = a00*a01 + a10*a11 + a20*a21;
    float m02 = a00*a02 + a10*a12 + a20*a22;
    float m11 = a01*a01 + a11*a11 + a21*a21;
    float m12 = a01*a02 + a11*a12 + a21*a22;
    float m22 = a02*a02 + a12*a12 + a22*a22;

    float q  = (m00 + m11 + m22) * (1.0f/3.0f);
    float b00 = m00 - q, b11 = m11 - q, b22 = m22 - q;
    float p1 = m01*m01 + m02*m02 + m12*m12;
    float p2 = b00*b00 + b11*b11 + b22*b22 + 2.0f*p1;
    float p  = sqrtf(p2 * (1.0f/6.0f));
    float detB = b00*(b11*b22 - m12*m12)
               - m01*(m01*b22 - m12*m02)
               + m02*(m01*m12 - b11*m02);
    float pinv = __fdividef(1.0f, fmaxf(p, 1e-20f));
    float r = 0.5f * detB * pinv * pinv * pinv;
    r = fminf(fmaxf(r, -1.0f), 1.0f);

    float ar = fabsf(r);
    float sq = sqrtf(1.0f - ar);
    float pl = 1.5707288f + ar * (-0.2121144f + ar * (0.0742610f - ar * 0.0187293f));
    float ac = sq * pl;
    float acr = (r >= 0.0f) ? ac : (3.14159265358979f - ac);
    float phi = acr * (1.0f/3.0f);                           // [0, pi/3]
    float mu1 = q + 2.0f*p*__cosf(phi);
    float mu3 = q + 2.0f*p*__cosf(phi + 2.0943951023931953f);
    float mu2 = 3.0f*q - mu1 - mu3;
    float l1 = sqrtf(fmaxf(mu1, 0.0f));
    float l2 = sqrtf(fmaxf(mu2, 0.0f));
    float l3 = sqrtf(fmaxf(mu3, 0.0f));

    float IU   = l1 + l2 + l3;
    float IIU  = l1*(l2 + l3) + l2*l3;
    float IIIU = l1*l2*l3;
    float denom = (l1 + l2) * (l1 + l3) * (l2 + l3);
    float dinv  = __fdividef(1.0f, fmaxf(denom, 1e-25f));
    float sd = (IU*IU - IIU) * dinv;
    float td = IU * IIIU * dinv;
    float nd = -dinv;

    float mm00 = m00*m00 + m01*m01 + m02*m02;
    float mm01 = m00*m01 + m01*m11 + m02*m12;
    float mm02 = m00*m02 + m01*m12 + m02*m22;
    float mm11 = m01*m01 + m11*m11 + m12*m12;
    float mm12 = m01*m02 + m11*m12 + m12*m22;
    float mm22 = m02*m02 + m12*m12 + m22*m22;

    vv[0] = nd*mm00 + sd*m00 + td;
    vv[1] = nd*mm01 + sd*m01;
    vv[2] = nd*mm02 + sd*m02;
    vv[3] = nd*mm11 + sd*m11 + td;
    vv[4] = nd*mm12 + sd*m12;
    vv[5] = nd*mm22 + sd*m22 + td;
}

// ---------------- main kernel (persistent, double-buffered) ----------------
__global__ __launch_bounds__(BLOCK) void vp_lattice_kernel(
    const float* __restrict__ lt,
    const float* __restrict__ pl0,
    const float* __restrict__ plat,
    const float* __restrict__ alpha_bars,
    const float* __restrict__ betas,
    const float* __restrict__ sigmas,
    const float* __restrict__ z_noise,
    const int*   __restrict__ t,
    float* __restrict__ out,
    int n,
    const float4* __restrict__ coefs,
    int use_ws)
{
    __shared__ __align__(16) float sW[WAVES * 2 * W_SZF];   // 57344 B

    const int lane = threadIdx.x & 63;
    const int wv   = threadIdx.x >> 6;
    const int wgid   = blockIdx.x * WAVES + wv;
    const int totalW = gridDim.x * WAVES;
    const int nchunks = n >> 6;                    // full 64-row chunks

    float* buf0 = sW + wv * 2 * W_SZF;
    float* buf1 = buf0 + W_SZF;

    if (wgid < nchunks) {
        // prologue: stage first chunk
        stage_chunk(lt, pl0, plat, z_noise, t, wgid * 64, lane, buf0);

        int par = 0;
        for (int c = wgid; c < nchunks; c += totalW) {
            float* cur = par ? buf1 : buf0;
            float* nxt = par ? buf0 : buf1;
            par ^= 1;

            // drain: only DMA(c) + 3 old NT stores outstanding here
            asm volatile("s_waitcnt vmcnt(0)" ::: "memory");
            __builtin_amdgcn_sched_barrier(0);

            // cf gather FIRST (so its auto-wait resolves at vmcnt(7))
            int ti = reinterpret_cast<const int*>(cur + W_T)[lane];
            float4 cf;
            if (use_ws) {
                cf = coefs[ti];
            } else {
                float beta_last = betas[NUM_STEPS - 1];
                float alpha = 1.0f - fminf(betas[ti], beta_last);
                float coef  = 1.0f / sqrtf(alpha + 1e-8f);
                float scale = (1.0f - alpha) / sqrtf(1.0f - alpha_bars[ti] + 1e-8f);
                cf.x = coef * (1.0f - scale);
                cf.y = 0.5f * coef * scale;
                cf.z = (ti > 1) ? sigmas[ti] : 0.0f;
            }
            __builtin_amdgcn_sched_barrier(0);     // keep cf issue above DMAs

            // prefetch next chunk (in flight during this chunk's compute)
            int cn = c + totalW;
            if (cn < nchunks)
                stage_chunk(lt, pl0, plat, z_noise, t, cn * 64, lane, nxt);

            // compute chunk c from LDS
            const int rowW = c * 64;
            float va[6];
            sqrtm_vec(cur + W_PLAT + lane * 9, va);   // stride 9: conflict-free

            const float* lr = cur + W_LT  + lane * 6; // stride 6: 2-way, free
            const float* qr = cur + W_PL0 + lane * 6;
            const float* zr = cur + W_ZN  + lane * 6;

            float o[6];
#pragma unroll
            for (int k = 0; k < 6; ++k) {
                float lc = lr[k];
                o[k] = cf.x * lc + cf.y * (va[k] + qr[k]) + cf.z * zr[k];
            }

            // non-temporal stores (streaming output)
            v2f* oG = (v2f*)(out + (size_t)(rowW + lane) * 6);
            v2f s0; s0.x = o[0]; s0.y = o[1];
            v2f s1; s1.x = o[2]; s1.y = o[3];
            v2f s2; s2.x = o[4]; s2.y = o[5];
            __builtin_nontemporal_store(s0, oG + 0);
            __builtin_nontemporal_store(s1, oG + 1);
            __builtin_nontemporal_store(s2, oG + 2);
        }
    }

    // ---- generic tail rows (none at B=2^20): grid-strided scalar ----
    for (int row = (nchunks << 6) + blockIdx.x * BLOCK + threadIdx.x;
         row < n; row += gridDim.x * BLOCK) {
        float ab[9];
#pragma unroll
        for (int k = 0; k < 9; ++k) ab[k] = plat[(size_t)row * 9 + k];
        float va[6];
        sqrtm_vec(ab, va);
        int ti = t[row];
        float4 cf;
        if (use_ws) {
            cf = coefs[ti];
        } else {
            float beta_last = betas[NUM_STEPS - 1];
            float alpha = 1.0f - fminf(betas[ti], beta_last);
            float coef  = 1.0f / sqrtf(alpha + 1e-8f);
            float scale = (1.0f - alpha) / sqrtf(1.0f - alpha_bars[ti] + 1e-8f);
            cf.x = coef * (1.0f - scale);
            cf.y = 0.5f * coef * scale;
            cf.z = (ti > 1) ? sigmas[ti] : 0.0f;
        }
        size_t b6 = (size_t)row * 6;
#pragma unroll
        for (int k = 0; k < 6; ++k) {
            float lc = lt[b6 + k];
            out[b6 + k] = cf.x * lc + cf.y * (va[k] + pl0[b6 + k]) + cf.z * z_noise[b6 + k];
        }
    }
}

extern "C" void kernel_launch(void* const* d_in, const int* in_sizes, int n_in,
                              void* d_out, int out_size, void* d_ws, size_t ws_size,
                              hipStream_t stream) {
    const float* lt         = (const float*)d_in[0];
    const float* pl0        = (const float*)d_in[1];
    const float* plat       = (const float*)d_in[2];
    const float* alpha_bars = (const float*)d_in[3];
    const float* betas      = (const float*)d_in[4];
    const float* sigmas     = (const float*)d_in[5];
    const float* z_noise    = (const float*)d_in[6];
    const int*   t          = (const int*)d_in[7];
    float* out = (float*)d_out;
    float4* ws = (float4*)d_ws;

    int n = in_sizes[0] / 6;   // B rows
    int use_ws = (ws != nullptr && ws_size >= (size_t)(TBL * sizeof(float4)));

    if (use_ws) {
        sched_kernel<<<(TBL + 255) / 256, 256, 0, stream>>>(alpha_bars, betas, sigmas, ws);
    }
    vp_lattice_kernel<<<GRID, BLOCK, 0, stream>>>(
        lt, pl0, plat, alpha_bars, betas, sigmas, z_noise, t, out, n, ws, use_ws);
}

// Round 10
// 151.478 us; speedup vs baseline: 1.0043x; 1.0043x over previous
//
#include <hip/hip_runtime.h>
#include <stdint.h>

// VP_lattice reverse step, B = 2^20 rows. Round-13:
//  R12 post-mortem: persistent dbuf landed at the same ~40us as R7/R8/
//  R10/R11 (5 structures, 40±2us). Re-derived: m13's 6.29TB/s copy is
//  SUM traffic -> read direction ~3.15TB/s; we run 112MB/40us = 2.8TB/s
//  read = 89% of that reference. R12's residual defect: vmcnt(0) drain
//  every iteration (T4 violation) retires the just-issued NT stores and
//  prefetch DMAs in-loop; prefetch distance only ~0.5 iteration.
//  R13 = R12 + counted waits + 2-deep prefetch:
//   - prologue stages chunks c0 AND c0+stride (buf0/buf1) -> ~2-iteration
//     latency cover.
//   - top-of-loop s_waitcnt: vmcnt(7) first iter / vmcnt(10) steady /
//     vmcnt(3) last (counts = ops newer than current chunk's 7 DMAs,
//     conservative against store-merging). NEVER vmcnt(0) in-loop.
//   - lgkmcnt(0)+sched_barrier before each stage protects the freed LDS
//     buffer from the async DMA overwrite.
//   - use_ws==0 fallback: vmcnt(0) (slow-safe, never taken).
//  Kill condition (pre-committed): if harness dur >= 151us, declare the
//  read-path roofline (~90% of copy-reference read rate) next round.
//  Math + DMA stream byte-identical to R10-R12 (passed, absmax 0.0156).

#define NUM_STEPS 1000
#define TBL 1008
#define BLOCK 256
#define WAVES 4
#define GRID 512             // 2 blocks/CU on 256 CUs

// per-wave LDS stream layout (floats); byte size 7168
#define W_PLAT 0             // 576 f  (2304 B)   stream [0,2304)
#define W_LT   576           // 384 f  (1536 B)   stream [2304,3840)
#define W_PL0  960           // 384 f             stream [3840,5376)
#define W_ZN   1344          // 384 f             stream [5376,6912)
#define W_T    1728          // 64 i              stream [6912,7168)
#define W_SZF  1792          // floats per buffer
#define AS1 __attribute__((address_space(1)))
#define AS3 __attribute__((address_space(3)))

typedef float v2f __attribute__((ext_vector_type(2)));

// NT (non-temporal) DMA: aux=2 sets the NT CPol bit -> L1 no-allocate.
__device__ __forceinline__ void dma16nt(const void* g, void* s) {
    __builtin_amdgcn_global_load_lds((const AS1 void*)g, (AS3 void*)s, 16, 0, 2);
}

// ---------------- schedule pre-kernel (runs once) ----------------
__global__ __launch_bounds__(256) void sched_kernel(
    const float* __restrict__ alpha_bars,
    const float* __restrict__ betas,
    const float* __restrict__ sigmas,
    float4* __restrict__ ws)         // packed {A, B, S, 0} per timestep
{
    int j = blockIdx.x * blockDim.x + threadIdx.x;
    if (j >= TBL) return;
    float4 v = make_float4(0.f, 0.f, 0.f, 0.f);
    if (j <= NUM_STEPS) {
        float beta_last = betas[NUM_STEPS - 1];              // betas[-2]
        float alpha = 1.0f - fminf(betas[j], beta_last);     // clamp_min
        float coef  = 1.0f / sqrtf(alpha + 1e-8f);
        float scale = (1.0f - alpha) / sqrtf(1.0f - alpha_bars[j] + 1e-8f);
        v.x = coef * (1.0f - scale);                         // A
        v.y = 0.5f * coef * scale;                           // B
        v.z = (j > 1) ? sigmas[j] : 0.0f;                    // S (z-gated)
    }
    ws[j] = v;
}

// ---- stage one 64-row chunk into a wave buffer (7x dma16nt) ----
__device__ __forceinline__ void stage_chunk(
    const float* __restrict__ lt,  const float* __restrict__ pl0,
    const float* __restrict__ plat, const float* __restrict__ z_noise,
    const int* __restrict__ t, int rowW, int lane, float* w)
{
    const char* pP = (const char*)(plat    + (size_t)rowW * 9);  // 2304 B
    const char* pL = (const char*)(lt      + (size_t)rowW * 6);  // 1536 B
    const char* pQ = (const char*)(pl0     + (size_t)rowW * 6);
    const char* pZ = (const char*)(z_noise + (size_t)rowW * 6);
    const char* pT = (const char*)(t + rowW);                    // 256 B
    char* wb = (char*)w;
    const int lb = lane * 16;
    // stream s = k*1024 + lane*16; boundaries P|L|Q|Z|T at
    // 2304|3840|5376|6912|7168 — per-lane source select (16B-aligned).
    dma16nt(pP + lb,        wb       );                      // k0: P
    dma16nt(pP + 1024 + lb, wb + 1024);                      // k1: P
    { int s = 2048 + lb;                                     // k2: P|L
      dma16nt((s < 2304) ? pP + s : pL + (s - 2304), wb + 2048); }
    { int s = 3072 + lb;                                     // k3: L|Q
      dma16nt((s < 3840) ? pL + (s - 2304) : pQ + (s - 3840), wb + 3072); }
    dma16nt(pQ + 256 + lb,  wb + 4096);                      // k4: Q
    { int s = 5120 + lb;                                     // k5: Q|Z
      dma16nt((s < 5376) ? pQ + (s - 3840) : pZ + (s - 5376), wb + 5120); }
    { int s = 6144 + lb;                                     // k6: Z|T
      dma16nt((s < 6912) ? pZ + (s - 5376) : pT + (s - 6912), wb + 6144); }
}

// ---- per-row math: vec = upper-tri of sqrtm(A^T A) ----
__device__ __forceinline__ void sqrtm_vec(const float* pr, float vv[6])
{
    float a00 = pr[0], a01 = pr[1], a02 = pr[2];
    float a10 = pr[3], a11 = pr[4], a12 = pr[5];
    float a20 = pr[6], a21 = pr[7], a22 = pr[8];

    float m00 = a00*a00 + a10*a10 + a20*a20;
    float m01 = a00*a01 + a10*a11 + a20*a21;
    float m02 = a00*a02 + a10*a12 + a20*a22;
    float m11 = a01*a01 + a11*a11 + a21*a21;
    float m12 = a01*a02 + a11*a12 + a21*a22;
    float m22 = a02*a02 + a12*a12 + a22*a22;

    float q  = (m00 + m11 + m22) * (1.0f/3.0f);
    float b00 = m00 - q, b11 = m11 - q, b22 = m22 - q;
    float p1 = m01*m01 + m02*m02 + m12*m12;
    float p2 = b00*b00 + b11*b11 + b22*b22 + 2.0f*p1;
    float p  = sqrtf(p2 * (1.0f/6.0f));
    float detB = b00*(b11*b22 - m12*m12)
               - m01*(m01*b22 - m12*m02)
               + m02*(m01*m12 - b11*m02);
    float pinv = __fdividef(1.0f, fmaxf(p, 1e-20f));
    float r = 0.5f * detB * pinv * pinv * pinv;
    r = fminf(fmaxf(r, -1.0f), 1.0f);

    float ar = fabsf(r);
    float sq = sqrtf(1.0f - ar);
    float pl = 1.5707288f + ar * (-0.2121144f + ar * (0.0742610f - ar * 0.0187293f));
    float ac = sq * pl;
    float acr = (r >= 0.0f) ? ac : (3.14159265358979f - ac);
    float phi = acr * (1.0f/3.0f);                           // [0, pi/3]
    float mu1 = q + 2.0f*p*__cosf(phi);
    float mu3 = q + 2.0f*p*__cosf(phi + 2.0943951023931953f);
    float mu2 = 3.0f*q - mu1 - mu3;
    float l1 = sqrtf(fmaxf(mu1, 0.0f));
    float l2 = sqrtf(fmaxf(mu2, 0.0f));
    float l3 = sqrtf(fmaxf(mu3, 0.0f));

    float IU   = l1 + l2 + l3;
    float IIU  = l1*(l2 + l3) + l2*l3;
    float IIIU = l1*l2*l3;
    float denom = (l1 + l2) * (l1 + l3) * (l2 + l3);
    float dinv  = __fdividef(1.0f, fmaxf(denom, 1e-25f));
    float sd = (IU*IU - IIU) * dinv;
    float td = IU * IIIU * dinv;
    float nd = -dinv;

    float mm00 = m00*m00 + m01*m01 + m02*m02;
    float mm01 = m00*m01 + m01*m11 + m02*m12;
    float mm02 = m00*m02 + m01*m12 + m02*m22;
    float mm11 = m01*m01 + m11*m11 + m12*m12;
    float mm12 = m01*m02 + m11*m12 + m12*m22;
    float mm22 = m02*m02 + m12*m12 + m22*m22;

    vv[0] = nd*mm00 + sd*m00 + td;
    vv[1] = nd*mm01 + sd*m01;
    vv[2] = nd*mm02 + sd*m02;
    vv[3] = nd*mm11 + sd*m11 + td;
    vv[4] = nd*mm12 + sd*m12;
    vv[5] = nd*mm22 + sd*m22 + td;
}

// ---------------- main kernel (persistent, counted-vmcnt pipeline) ----------
__global__ __launch_bounds__(BLOCK) void vp_lattice_kernel(
    const float* __restrict__ lt,
    const float* __restrict__ pl0,
    const float* __restrict__ plat,
    const float* __restrict__ alpha_bars,
    const float* __restrict__ betas,
    const float* __restrict__ sigmas,
    const float* __restrict__ z_noise,
    const int*   __restrict__ t,
    float* __restrict__ out,
    int n,
    const float4* __restrict__ coefs,
    int use_ws)
{
    __shared__ __align__(16) float sW[WAVES * 2 * W_SZF];   // 57344 B

    const int lane = threadIdx.x & 63;
    const int wv   = threadIdx.x >> 6;
    const int wgid   = blockIdx.x * WAVES + wv;
    const int totalW = gridDim.x * WAVES;
    const int nchunks = n >> 6;                    // full 64-row chunks

    float* buf0 = sW + wv * 2 * W_SZF;
    float* buf1 = buf0 + W_SZF;

    if (wgid < nchunks) {
        // prologue: stage 2 chunks ahead
        stage_chunk(lt, pl0, plat, z_noise, t, wgid * 64, lane, buf0);
        const int c1 = wgid + totalW;
        const bool have2 = (c1 < nchunks);
        if (have2)
            stage_chunk(lt, pl0, plat, z_noise, t, c1 * 64, lane, buf1);

        int par = 0;
        int it  = 0;
        for (int c = wgid; c < nchunks; c += totalW, ++it) {
            float* cur = par ? buf1 : buf0;
            par ^= 1;
            const bool nextStaged = (c + totalW < nchunks);

            // counted drain: wait ONLY the current chunk's 7 DMAs.
            // newer-than-them ops kept in flight:
            //   first iter: D_next(7) -> vmcnt(7) (or 0 if none)
            //   steady:     G(1)+S(<=3)+D_next(7) -> vmcnt(10) (safe if S merges)
            //   last:       G(1)+S(<=3) -> vmcnt(3)
            if (!use_ws) {
                asm volatile("s_waitcnt vmcnt(0)" ::: "memory");
            } else if (it == 0) {
                if (have2) { asm volatile("s_waitcnt vmcnt(7)" ::: "memory"); }
                else       { asm volatile("s_waitcnt vmcnt(0)" ::: "memory"); }
            } else if (nextStaged) {
                asm volatile("s_waitcnt vmcnt(10)" ::: "memory");
            } else {
                asm volatile("s_waitcnt vmcnt(3)" ::: "memory");
            }
            __builtin_amdgcn_sched_barrier(0);

            // timestep + coefficients (16 KB packed table: cached, reused)
            int ti = reinterpret_cast<const int*>(cur + W_T)[lane];
            float4 cf;
            if (use_ws) {
                cf = coefs[ti];
            } else {
                float beta_last = betas[NUM_STEPS - 1];
                float alpha = 1.0f - fminf(betas[ti], beta_last);
                float coef  = 1.0f / sqrtf(alpha + 1e-8f);
                float scale = (1.0f - alpha) / sqrtf(1.0f - alpha_bars[ti] + 1e-8f);
                cf.x = coef * (1.0f - scale);
                cf.y = 0.5f * coef * scale;
                cf.z = (ti > 1) ? sigmas[ti] : 0.0f;
            }

            // compute chunk c from LDS
            const int rowW = c * 64;
            float va[6];
            sqrtm_vec(cur + W_PLAT + lane * 9, va);   // stride 9: conflict-free

            const float* lr = cur + W_LT  + lane * 6; // stride 6: 2-way, free
            const float* qr = cur + W_PL0 + lane * 6;
            const float* zr = cur + W_ZN  + lane * 6;

            float o[6];
#pragma unroll
            for (int k = 0; k < 6; ++k) {
                float lc = lr[k];
                o[k] = cf.x * lc + cf.y * (va[k] + qr[k]) + cf.z * zr[k];
            }

            // non-temporal stores (streaming output, never drained in-loop)
            v2f* oG = (v2f*)(out + (size_t)(rowW + lane) * 6);
            v2f s0; s0.x = o[0]; s0.y = o[1];
            v2f s1; s1.x = o[2]; s1.y = o[3];
            v2f s2; s2.x = o[4]; s2.y = o[5];
            __builtin_nontemporal_store(s0, oG + 0);
            __builtin_nontemporal_store(s1, oG + 1);
            __builtin_nontemporal_store(s2, oG + 2);

            // prefetch chunk c + 2*stride into the buffer just freed.
            // lgkmcnt(0): all ds_reads retired before async DMA overwrite.
            int cn = c + 2 * totalW;
            if (cn < nchunks) {
                asm volatile("s_waitcnt lgkmcnt(0)" ::: "memory");
                __builtin_amdgcn_sched_barrier(0);
                stage_chunk(lt, pl0, plat, z_noise, t, cn * 64, lane, cur);
            }
        }
    }

    // ---- generic tail rows (none at B=2^20): grid-strided scalar ----
    for (int row = (nchunks << 6) + blockIdx.x * BLOCK + threadIdx.x;
         row < n; row += gridDim.x * BLOCK) {
        float ab[9];
#pragma unroll
        for (int k = 0; k < 9; ++k) ab[k] = plat[(size_t)row * 9 + k];
        float va[6];
        sqrtm_vec(ab, va);
        int ti = t[row];
        float4 cf;
        if (use_ws) {
            cf = coefs[ti];
        } else {
            float beta_last = betas[NUM_STEPS - 1];
            float alpha = 1.0f - fminf(betas[ti], beta_last);
            float coef  = 1.0f / sqrtf(alpha + 1e-8f);
            float scale = (1.0f - alpha) / sqrtf(1.0f - alpha_bars[ti] + 1e-8f);
            cf.x = coef * (1.0f - scale);
            cf.y = 0.5f * coef * scale;
            cf.z = (ti > 1) ? sigmas[ti] : 0.0f;
        }
        size_t b6 = (size_t)row * 6;
#pragma unroll
        for (int k = 0; k < 6; ++k) {
            float lc = lt[b6 + k];
            out[b6 + k] = cf.x * lc + cf.y * (va[k] + pl0[b6 + k]) + cf.z * z_noise[b6 + k];
        }
    }
}

extern "C" void kernel_launch(void* const* d_in, const int* in_sizes, int n_in,
                              void* d_out, int out_size, void* d_ws, size_t ws_size,
                              hipStream_t stream) {
    const float* lt         = (const float*)d_in[0];
    const float* pl0        = (const float*)d_in[1];
    const float* plat       = (const float*)d_in[2];
    const float* alpha_bars = (const float*)d_in[3];
    const float* betas      = (const float*)d_in[4];
    const float* sigmas     = (const float*)d_in[5];
    const float* z_noise    = (const float*)d_in[6];
    const int*   t          = (const int*)d_in[7];
    float* out = (float*)d_out;
    float4* ws = (float4*)d_ws;

    int n = in_sizes[0] / 6;   // B rows
    int use_ws = (ws != nullptr && ws_size >= (size_t)(TBL * sizeof(float4)));

    if (use_ws) {
        sched_kernel<<<(TBL + 255) / 256, 256, 0, stream>>>(alpha_bars, betas, sigmas, ws);
    }
    vp_lattice_kernel<<<GRID, BLOCK, 0, stream>>>(
        lt, pl0, plat, alpha_bars, betas, sigmas, z_noise, t, out, n, ws, use_ws);
}